// Round 4
// baseline (271.599 us; speedup 1.0000x reference)
//
#include <hip/hip_runtime.h>
#include <hip/hip_bf16.h>
#include <math.h>

#define SEQ 4096
#define HID 1024
#define DH  64
#define NB  8
#define QSCALE 0.18033688011112042f   // 0.125 * log2(e): folds softmax scale + exp->exp2

typedef unsigned short ushort_t;
typedef unsigned int   uint_t;
typedef __attribute__((ext_vector_type(8))) short  bf16x8;
typedef __attribute__((ext_vector_type(4))) float  f32x4;
typedef __attribute__((ext_vector_type(4))) uint_t u32x4;

static __device__ __forceinline__ ushort_t f2bf(float f) {
    __hip_bfloat16 h = __float2bfloat16(f);   // RNE
    return *reinterpret_cast<ushort_t*>(&h);
}
// fast round-to-nearest bf16 (no NaN path; inputs are finite >= 0)
static __device__ __forceinline__ ushort_t f2bf_fast(float f) {
    uint_t u = __float_as_uint(f);
    return (ushort_t)((u + 0x8000u) >> 16);
}

// async global->LDS DMA, 16 B per lane; lds dest = wave-uniform base + lane*16
static __device__ __forceinline__ void gld_lds16(const void* g, void* s) {
    __builtin_amdgcn_global_load_lds(
        (const __attribute__((address_space(1))) void*)g,
        (__attribute__((address_space(3))) void*)s, 16, 0, 0);
}

// ---------------------------------------------------------------------------
// Kernel 0: build wts = [Wq*QSCALE | Wk | Wv] transposed to [col][k], bf16,
// pre-swizzled per 64-k tile so proj can stage it as a flat copy.
// ---------------------------------------------------------------------------
__global__ __launch_bounds__(256) void prep_w(
    const float* __restrict__ Wq, const float* __restrict__ Wk,
    const float* __restrict__ Wv, ushort_t* __restrict__ wts)
{
    __shared__ ushort_t tr[64][72];   // [k][c] bf16
    const int bx   = blockIdx.x;      // 48 = 3 mats x 16 k-tiles
    const int mmat = bx >> 4;
    const int kt   = bx & 15;
    const float* W  = (mmat == 0) ? Wq : (mmat == 1) ? Wk : Wv;
    const float  sc = (mmat == 0) ? QSCALE : 1.0f;

    const int t  = threadIdx.x;
    const int kr = t >> 2, kc = (t & 3) * 16;
    const float* src = W + (size_t)(kt * 64 + kr) * DH + kc;
    float4 a0 = *(const float4*)(src);
    float4 a1 = *(const float4*)(src + 4);
    float4 a2 = *(const float4*)(src + 8);
    float4 a3 = *(const float4*)(src + 12);
    float vv[16] = {a0.x,a0.y,a0.z,a0.w, a1.x,a1.y,a1.z,a1.w,
                    a2.x,a2.y,a2.z,a2.w, a3.x,a3.y,a3.z,a3.w};
    #pragma unroll
    for (int i = 0; i < 16; ++i) tr[kr][kc + i] = f2bf(vv[i] * sc);
    __syncthreads();

    const int cl = t >> 2, jc = (t & 3) * 16;
    const int c  = mmat * 64 + cl;
    ushort_t* dst = wts + kt * 12288 + c * 64;
    #pragma unroll
    for (int jj = 0; jj < 16; ++jj) {
        int j = jc + jj;
        dst[((j >> 3) ^ (cl & 7)) * 8 + (j & 7)] = tr[j][cl];
    }
}

// ---------------------------------------------------------------------------
// Kernel 1: fused QKV projection, bf16 MFMA, double-buffered (1 barrier/iter).
// Outputs: qimg natural [s][d] bf16 (Q pre-scaled by QSCALE);
//          kimg/vimg as pre-swizzled per-64-row tile images (= attn LDS image).
// ---------------------------------------------------------------------------
__global__ __launch_bounds__(256) void qkv_proj(
    const float* __restrict__ x, const ushort_t* __restrict__ wts,
    const float* __restrict__ bq, const float* __restrict__ bk,
    const float* __restrict__ bv,
    ushort_t* __restrict__ qimg, ushort_t* __restrict__ kimg,
    ushort_t* __restrict__ vimg)
{
    __shared__ ushort_t xs[2][64][72];
    __shared__ ushort_t bw[2][12288];

    const int t  = threadIdx.x;
    const int w  = t >> 6, l = t & 63, lr = l & 15, lg = l >> 4;
    const int row0 = blockIdx.x * 64;
    const int sxr = t >> 2, sxc = (t & 3) * 16;
    const int ch0 = (lg ^ (lr & 7)) * 8;
    const int ch1 = ((lg + 4) ^ (lr & 7)) * 8;

    f32x4 acc[4][3];
    #pragma unroll
    for (int i = 0; i < 4; ++i)
        #pragma unroll
        for (int j = 0; j < 3; ++j) acc[i][j] = (f32x4){0.f,0.f,0.f,0.f};

    float4 Xf[4];
    u32x4  Bf[6];
    {   // prologue: tile 0 loads
        const float* xr = x + (size_t)(row0 + sxr) * HID + sxc;
        Xf[0] = *(const float4*)(xr);      Xf[1] = *(const float4*)(xr + 4);
        Xf[2] = *(const float4*)(xr + 8);  Xf[3] = *(const float4*)(xr + 12);
        const char* bsrc = (const char*)wts + t * 16;
        #pragma unroll
        for (int i = 0; i < 6; ++i) Bf[i] = *(const u32x4*)(bsrc + i * 4096);
    }

    for (int kt = 0; kt < 16; ++kt) {
        const int buf = kt & 1;
        // A: write staged regs -> LDS buf
        {
            u32x4 p0, p1;
            p0.x = (uint_t)f2bf(Xf[0].x) | ((uint_t)f2bf(Xf[0].y) << 16);
            p0.y = (uint_t)f2bf(Xf[0].z) | ((uint_t)f2bf(Xf[0].w) << 16);
            p0.z = (uint_t)f2bf(Xf[1].x) | ((uint_t)f2bf(Xf[1].y) << 16);
            p0.w = (uint_t)f2bf(Xf[1].z) | ((uint_t)f2bf(Xf[1].w) << 16);
            p1.x = (uint_t)f2bf(Xf[2].x) | ((uint_t)f2bf(Xf[2].y) << 16);
            p1.y = (uint_t)f2bf(Xf[2].z) | ((uint_t)f2bf(Xf[2].w) << 16);
            p1.z = (uint_t)f2bf(Xf[3].x) | ((uint_t)f2bf(Xf[3].y) << 16);
            p1.w = (uint_t)f2bf(Xf[3].z) | ((uint_t)f2bf(Xf[3].w) << 16);
            *(u32x4*)&xs[buf][sxr][sxc]     = p0;
            *(u32x4*)&xs[buf][sxr][sxc + 8] = p1;
            char* bdst = (char*)&bw[buf][0] + t * 16;
            #pragma unroll
            for (int i = 0; i < 6; ++i) *(u32x4*)(bdst + i * 4096) = Bf[i];
        }
        __syncthreads();
        // C: prefetch tile kt+1 (in flight across compute)
        if (kt < 15) {
            const float* xr = x + (size_t)(row0 + sxr) * HID + (kt + 1) * 64 + sxc;
            Xf[0] = *(const float4*)(xr);      Xf[1] = *(const float4*)(xr + 4);
            Xf[2] = *(const float4*)(xr + 8);  Xf[3] = *(const float4*)(xr + 12);
            const char* bsrc = (const char*)wts + (kt + 1) * 24576 + t * 16;
            #pragma unroll
            for (int i = 0; i < 6; ++i) Bf[i] = *(const u32x4*)(bsrc + i * 4096);
        }
        // D: compute tile kt
        bf16x8 af0[4], af1[4];
        #pragma unroll
        for (int rt = 0; rt < 4; ++rt) {
            af0[rt] = *(bf16x8*)&xs[buf][rt * 16 + lr][lg * 8];
            af1[rt] = *(bf16x8*)&xs[buf][rt * 16 + lr][lg * 8 + 32];
        }
        #pragma unroll
        for (int ctl = 0; ctl < 3; ++ctl) {
            const int c = (w * 3 + ctl) * 16 + lr;
            bf16x8 b0 = *(bf16x8*)&bw[buf][c * 64 + ch0];
            bf16x8 b1 = *(bf16x8*)&bw[buf][c * 64 + ch1];
            #pragma unroll
            for (int rt = 0; rt < 4; ++rt) {
                acc[rt][ctl] = __builtin_amdgcn_mfma_f32_16x16x32_bf16(
                    af0[rt], b0, acc[rt][ctl], 0, 0, 0);
                acc[rt][ctl] = __builtin_amdgcn_mfma_f32_16x16x32_bf16(
                    af1[rt], b1, acc[rt][ctl], 0, 0, 0);
            }
        }
    }

    // epilogue: +bias, cast, scatter to layout images
    #pragma unroll
    for (int ctl = 0; ctl < 3; ++ctl) {
        const int c    = (w * 3 + ctl) * 16 + lr;
        const int mmat = c >> 6;
        const int cc   = c & 63;
        const float* bp = (mmat == 0) ? bq : (mmat == 1) ? bk : bv;
        const float bias = bp[cc] * (mmat == 0 ? QSCALE : 1.0f);
        #pragma unroll
        for (int rt = 0; rt < 4; ++rt)
            #pragma unroll
            for (int r = 0; r < 4; ++r) {
                const int s = row0 + rt * 16 + lg * 4 + r;
                const ushort_t v = f2bf(acc[rt][ctl][r] + bias);
                if (mmat == 0)
                    qimg[(size_t)s * 64 + cc] = v;
                else if (mmat == 1)
                    kimg[(size_t)(s >> 6) * 4096 + (s & 63) * 64 +
                         ((cc >> 3) ^ (s & 7)) * 8 + (cc & 7)] = v;
                else
                    vimg[(size_t)(s >> 6) * 4096 + (size_t)cc * 64 +
                         (((s & 63) >> 3) ^ (cc & 7)) * 8 + (s & 7)] = v;
            }
    }
}

// ---------------------------------------------------------------------------
// Kernel 2: causal flash attention, bf16 MFMA.
// Pipelined: iter kt stages tile kt+1 (async DMA, triple-buffered LDS),
// computes QK(kt) into fresh accs, and runs exp+PV on tile kt-1 whose
// scores retired a full iteration ago. Diagonal handled in peeled drain.
// No running max; l via MFMA against all-ones B fragment.
// ---------------------------------------------------------------------------
__global__ __launch_bounds__(256) void attn(
    const ushort_t* __restrict__ qimg, const ushort_t* __restrict__ kimg,
    const ushort_t* __restrict__ vimg, float* __restrict__ outg)
{
    __shared__ ushort_t kvs[3][8192];   // per slot: K img bytes 0..8191, V img 8192..16383
    __shared__ ushort_t ps[64][76];     // wave w owns rows 16w..16w+15

    const int t  = threadIdx.x;
    const int w  = t >> 6, l = t & 63, lr = l & 15, lg = l >> 4;
    const int bx = blockIdx.x;          // longest-first (LPT)
    const int qt = 63 - (bx >> 3);
    const int b  = bx & 7;
    const int q0 = qt * 64;
    const int ch0 = (lg ^ (lr & 7)) * 8;
    const int ch1 = ((lg + 4) ^ (lr & 7)) * 8;

    bf16x8 qf0, qf1;
    {
        const ushort_t* qp = qimg + (size_t)(b * SEQ + q0 + w * 16 + lr) * 64 + lg * 8;
        qf0 = *(const bf16x8*)(qp);
        qf1 = *(const bf16x8*)(qp + 32);
    }
    bf16x8 ones;
    #pragma unroll
    for (int i = 0; i < 8; ++i) ones[i] = (short)0x3F80;   // bf16 1.0

    f32x4 o[4], accl, s[4];
    #pragma unroll
    for (int dt = 0; dt < 4; ++dt) o[dt] = (f32x4){0.f,0.f,0.f,0.f};
    accl = (f32x4){0.f,0.f,0.f,0.f};
    #pragma unroll
    for (int ct = 0; ct < 4; ++ct) s[ct] = (f32x4){0.f,0.f,0.f,0.f};

    const char* kbase = (const char*)kimg + (size_t)b * 524288;  // 64 tiles * 8192 B
    const char* vbase = (const char*)vimg + (size_t)b * 524288;
    const int wo = w * 1024;          // wave-uniform LDS/global sub-offset
    const int lo = l * 16;            // lane global offset

    // prologue: stage tile 0 -> slot 0
    {
        char* lk = (char*)&kvs[0][0];
        gld_lds16(kbase + wo + lo,        lk + wo);
        gld_lds16(kbase + wo + lo + 4096, lk + wo + 4096);
        gld_lds16(vbase + wo + lo,        lk + wo + 8192);
        gld_lds16(vbase + wo + lo + 4096, lk + wo + 12288);
    }

    for (int kt = 0; kt <= qt; ++kt) {
        const int cur = kt % 3;
        __syncthreads();                      // drains DMA for tile kt
        if (kt < qt) {                        // stage tile kt+1
            const int   nxt = (kt + 1) % 3;
            const char* ks  = kbase + (size_t)(kt + 1) * 8192;
            const char* vs  = vbase + (size_t)(kt + 1) * 8192;
            char*       lk  = (char*)&kvs[nxt][0];
            gld_lds16(ks + wo + lo,        lk + wo);
            gld_lds16(ks + wo + lo + 4096, lk + wo + 4096);
            gld_lds16(vs + wo + lo,        lk + wo + 8192);
            gld_lds16(vs + wo + lo + 8192 - 4096, lk + wo + 12288);
        }

        // K fragment reads for tile kt
        const ushort_t* kb = &kvs[cur][0];
        bf16x8 kf0[4], kf1[4];
        #pragma unroll
        for (int ct = 0; ct < 4; ++ct) {
            const int rowb = (ct * 16 + lr) * 64;
            kf0[ct] = *(const bf16x8*)(kb + rowb + ch0);
            kf1[ct] = *(const bf16x8*)(kb + rowb + ch1);
        }

        // exp phase on tile kt-1 (scores retired last iter; never diagonal)
        if (kt > 0) {
            #pragma unroll
            for (int r = 0; r < 4; ++r)
                #pragma unroll
                for (int ct = 0; ct < 4; ++ct) {
                    float p = __builtin_amdgcn_exp2f(s[ct][r]);
                    ps[w * 16 + lg * 4 + r][ct * 16 + lr] = f2bf_fast(p);
                }
        }

        // QK for tile kt into fresh accumulators
        f32x4 sn[4];
        #pragma unroll
        for (int ct = 0; ct < 4; ++ct) {
            sn[ct] = (f32x4){0.f,0.f,0.f,0.f};
            sn[ct] = __builtin_amdgcn_mfma_f32_16x16x32_bf16(qf0, kf0[ct], sn[ct], 0, 0, 0);
            sn[ct] = __builtin_amdgcn_mfma_f32_16x16x32_bf16(qf1, kf1[ct], sn[ct], 0, 0, 0);
        }

        // PV phase for tile kt-1
        if (kt > 0) {
            bf16x8 pf0 = *(const bf16x8*)&ps[w * 16 + lr][lg * 8];
            bf16x8 pf1 = *(const bf16x8*)&ps[w * 16 + lr][lg * 8 + 32];
            accl = __builtin_amdgcn_mfma_f32_16x16x32_bf16(pf0, ones, accl, 0, 0, 0);
            accl = __builtin_amdgcn_mfma_f32_16x16x32_bf16(pf1, ones, accl, 0, 0, 0);
            const ushort_t* vb = &kvs[(kt - 1) % 3][4096];
            #pragma unroll
            for (int dt = 0; dt < 4; ++dt) {
                const int rowb = (dt * 16 + lr) * 64;
                bf16x8 vf0 = *(const bf16x8*)(vb + rowb + ch0);
                bf16x8 vf1 = *(const bf16x8*)(vb + rowb + ch1);
                o[dt] = __builtin_amdgcn_mfma_f32_16x16x32_bf16(pf0, vf0, o[dt], 0, 0, 0);
                o[dt] = __builtin_amdgcn_mfma_f32_16x16x32_bf16(pf1, vf1, o[dt], 0, 0, 0);
            }
        }
        #pragma unroll
        for (int ct = 0; ct < 4; ++ct) s[ct] = sn[ct];
    }

    // drain: exp + PV for tile qt (diagonal -> causal mask)
    {
        #pragma unroll
        for (int r = 0; r < 4; ++r) {
            const int qr = w * 16 + lg * 4 + r;
            #pragma unroll
            for (int ct = 0; ct < 4; ++ct) {
                float sv = ((ct * 16 + lr) > qr) ? -INFINITY : s[ct][r];
                float p  = __builtin_amdgcn_exp2f(sv);
                ps[w * 16 + lg * 4 + r][ct * 16 + lr] = f2bf_fast(p);
            }
        }
        bf16x8 pf0 = *(const bf16x8*)&ps[w * 16 + lr][lg * 8];
        bf16x8 pf1 = *(const bf16x8*)&ps[w * 16 + lr][lg * 8 + 32];
        accl = __builtin_amdgcn_mfma_f32_16x16x32_bf16(pf0, ones, accl, 0, 0, 0);
        accl = __builtin_amdgcn_mfma_f32_16x16x32_bf16(pf1, ones, accl, 0, 0, 0);
        const ushort_t* vb = &kvs[qt % 3][4096];
        #pragma unroll
        for (int dt = 0; dt < 4; ++dt) {
            const int rowb = (dt * 16 + lr) * 64;
            bf16x8 vf0 = *(const bf16x8*)(vb + rowb + ch0);
            bf16x8 vf1 = *(const bf16x8*)(vb + rowb + ch1);
            o[dt] = __builtin_amdgcn_mfma_f32_16x16x32_bf16(pf0, vf0, o[dt], 0, 0, 0);
            o[dt] = __builtin_amdgcn_mfma_f32_16x16x32_bf16(pf1, vf1, o[dt], 0, 0, 0);
        }
    }

    #pragma unroll
    for (int r = 0; r < 4; ++r) {
        const float inv = 1.0f / accl[r];
        float* orow = outg + ((size_t)b * SEQ + q0 + w * 16 + lg * 4 + r) * 64;
        #pragma unroll
        for (int dt = 0; dt < 4; ++dt)
            orow[dt * 16 + lr] = o[dt][r] * inv;
    }
}

extern "C" void kernel_launch(void* const* d_in, const int* in_sizes, int n_in,
                              void* d_out, int out_size, void* d_ws, size_t ws_size,
                              hipStream_t stream) {
    const float* x  = (const float*)d_in[0];
    const float* Wq = (const float*)d_in[1];
    const float* bq = (const float*)d_in[2];
    const float* Wk = (const float*)d_in[3];
    const float* bk = (const float*)d_in[4];
    const float* Wv = (const float*)d_in[5];
    const float* bv = (const float*)d_in[6];
    float* out = (float*)d_out;

    const size_t per = (size_t)NB * SEQ * DH;   // 2,097,152 bf16 elems = 4 MB
    ushort_t* q   = (ushort_t*)d_ws;
    ushort_t* k   = q + per;
    ushort_t* v   = k + per;
    ushort_t* wts = v + per;                    // 196,608 bf16 = 384 KB

    prep_w  <<<dim3(48),  256, 0, stream>>>(Wq, Wk, Wv, wts);
    qkv_proj<<<dim3(512), 256, 0, stream>>>(x, wts, bq, bk, bv, q, k, v);
    attn    <<<dim3(512), 256, 0, stream>>>(q, k, v, out);
}